// Round 8
// baseline (703.725 us; speedup 1.0000x reference)
//
#include <hip/hip_runtime.h>
#include <hip/hip_bf16.h>
#include <math.h>

#define M_TOK 16384
#define N_EXP 256
#define K_DIM 7168
#define BM 32
#define BK 32
#define KSTEPS (K_DIM / BK)  /* 224 */
#define WTILE 32768          /* bytes per k-step W image: 16KB hi + 16KB lo (fp16) */
#define TOPK 8
#define SX 4096.0f           /* x prescale (exact pow2) */
#define SW 16384.0f          /* w prescale (exact pow2) */
#define DESCALE 1.4901161193847656e-08f /* 2^-26 = 1/(SX*SW) */

typedef __attribute__((ext_vector_type(8))) _Float16 half8;
typedef __attribute__((ext_vector_type(4))) _Float16 half4;
typedef __attribute__((ext_vector_type(4))) float f32x4;

// 2-way fp16 split of prescaled fp32: v = h + l + r, |r| <= 2^-24 |v|.
__device__ __forceinline__ void cvt8_2(const float* v, half8& h, half8& l) {
#pragma unroll
  for (int i = 0; i < 8; ++i) {
    _Float16 a = (_Float16)v[i];
    float r = v[i] - (float)a;
    h[i] = a;
    l[i] = (_Float16)r;
  }
}
__device__ __forceinline__ void cvt4_2(const float* v, half4& h, half4& l) {
#pragma unroll
  for (int i = 0; i < 4; ++i) {
    _Float16 a = (_Float16)v[i];
    float r = v[i] - (float)a;
    h[i] = a;
    l[i] = (_Float16)r;
  }
}

// monotone fp32 -> u32 key (no NaN inputs), pack with inverted index for
// lax.top_k tie-break (descending value, lowest index first on exact ties)
__device__ __forceinline__ unsigned long long pack_ci(float key, int idx) {
  unsigned int u = __builtin_bit_cast(unsigned int, key);
  u = (u & 0x80000000u) ? ~u : (u | 0x80000000u);
  return ((unsigned long long)u << 32) | (unsigned)(255 - idx);
}
__device__ __forceinline__ unsigned long long shflx64(unsigned long long v, int off) {
  int lo = __shfl_xor((int)(unsigned)(v & 0xffffffffull), off);
  int hi = __shfl_xor((int)(unsigned)(v >> 32), off);
  return ((unsigned long long)(unsigned)hi << 32) | (unsigned)lo;
}

// gate_weight fp32 [256][7168] -> per-kstep swizzled fp16 images in ws.
// Image t (32KB): hi plane [256 rows][64B] at +0, lo plane at +16384.
// byte col of 16B granule kc: (kc*16) ^ ((e&6)<<3).
// (Swizzle kept for image-format compatibility; reads use the same map.)
__global__ void prep_w_kernel(const float* __restrict__ W, unsigned char* __restrict__ ws) {
  int t = blockIdx.x;    // kstep
  int e = threadIdx.x;   // expert row
  const float* src = W + (size_t)e * K_DIM + t * BK;
  unsigned char* dst = ws + (size_t)t * WTILE;
#pragma unroll
  for (int kc = 0; kc < 4; ++kc) {
    float v[8];
    float4 a = ((const float4*)src)[kc * 2];
    float4 b = ((const float4*)src)[kc * 2 + 1];
    v[0] = a.x * SW; v[1] = a.y * SW; v[2] = a.z * SW; v[3] = a.w * SW;
    v[4] = b.x * SW; v[5] = b.y * SW; v[6] = b.z * SW; v[7] = b.w * SW;
    half8 h, l;
    cvt8_2(v, h, l);
    int col = (kc * 16) ^ ((e & 6) << 3);
    *(half8*)(dst + e * 64 + col) = h;
    *(half8*)(dst + 16384 + e * 64 + col) = l;
  }
}

template <bool USE_WS>
__global__ __launch_bounds__(256, 4) void gate_kernel(
    const float* __restrict__ X,
    const float* __restrict__ Wg,
    const unsigned char* __restrict__ ws,
    const float* __restrict__ bias,
    float* __restrict__ out) {
  // LDS 33280B/block -> 4 blocks/CU. A bufs [2][4KB] at 0 (hi 2KB, lo 2KB);
  // W comes straight from global (ws) into registers — no LDS for W.
  // Epilogue reuses 0..33279 as scores [32][260] f32.
  __shared__ unsigned char smem[33280] __attribute__((aligned(16)));

  const int tid = threadIdx.x;
  const int lane = tid & 63;
  const int wid = tid >> 6;   // 0..3 = N group: experts wid*64..+64
  const int lr = lane & 15;
  const int lg = lane >> 4;
  const int m0 = blockIdx.x * BM;

  // A frag byte offsets in LDS (row base+lr, 16B k-chunk lg, XOR-swizzled).
  int aOff[2];
#pragma unroll
  for (int m = 0; m < 2; ++m) {
    int r = m * 16 + lr;
    aOff[m] = r * 64 + ((lg * 16) ^ ((r & 6) << 3));
  }
  // W frag byte offsets within a kstep image (per-lane, constant over t).
  int bWOff[4];
#pragma unroll
  for (int n = 0; n < 4; ++n) {
    int e = wid * 64 + n * 16 + lr;
    bWOff[n] = e * 64 + ((lg * 16) ^ ((e & 6) << 3));
  }

  // X staging: 256 threads cover 32 rows x 8 chunks of 4 floats
  const int xr = tid >> 3;
  const int xkc = tid & 7;
  const float* xsrc = X + (size_t)(m0 + xr) * K_DIM + xkc * 4;
  const int xcol = (xkc * 8) ^ ((xr & 6) << 3);

  auto load_x = [&](int t, float4& dst) {
    dst = *(const float4*)(xsrc + (size_t)t * BK);
  };
  auto write_x = [&](int b, const float4& xv) {
    float v[4] = {xv.x * SX, xv.y * SX, xv.z * SX, xv.w * SX};
    half4 h, l;
    cvt4_2(v, h, l);
    unsigned char* Ab = smem + b * 4096;
    *(half4*)(Ab + xr * 64 + xcol) = h;
    *(half4*)(Ab + 2048 + xr * 64 + xcol) = l;
  };

  f32x4 acc[2][4];   // xh*wh (main term)
  f32x4 accc[2][4];  // correction terms xh*wl + xl*wh (<= 2^-12 of main)
#pragma unroll
  for (int m = 0; m < 2; ++m)
#pragma unroll
    for (int n = 0; n < 4; ++n) {
      acc[m][n] = (f32x4){0.f, 0.f, 0.f, 0.f};
      accc[m][n] = (f32x4){0.f, 0.f, 0.f, 0.f};
    }

  // One pipeline stage. Consumes xcons (=X(t+1)), loads X(t+2) into xload.
  // W frags for step t load global->regs at top; only A lives in LDS, so the
  // pre-barrier wait is lgkmcnt(0) only (X(t+2) stays in flight across it;
  // W loads are wave-private and compiler-counted before their MFMAs).
  auto body = [&](int t, float4& xload, const float4& xcons) {
    const int cur = t & 1, nxt = cur ^ 1;

    // ---- W fragments: global (L2) -> regs, 8 x 16B coalesced per wave
    half8 wh[4], wl[4];
    if constexpr (USE_WS) {
      const unsigned char* img = ws + (size_t)t * WTILE;
#pragma unroll
      for (int n = 0; n < 4; ++n) wh[n] = *(const half8*)(img + bWOff[n]);
#pragma unroll
      for (int n = 0; n < 4; ++n) wl[n] = *(const half8*)(img + 16384 + bWOff[n]);
    } else {
      // fallback: 8 fp32 per fragment from Wg + on-the-fly split
#pragma unroll
      for (int n = 0; n < 4; ++n) {
        int e = wid * 64 + n * 16 + lr;
        const float* src = Wg + (size_t)e * K_DIM + (size_t)t * BK + lg * 8;
        float v[8];
        float4 a = ((const float4*)src)[0];
        float4 bq = ((const float4*)src)[1];
        v[0] = a.x * SW; v[1] = a.y * SW; v[2] = a.z * SW; v[3] = a.w * SW;
        v[4] = bq.x * SW; v[5] = bq.y * SW; v[6] = bq.z * SW; v[7] = bq.w * SW;
        cvt8_2(v, wh[n], wl[n]);
      }
    }

    if (t + 2 < KSTEPS) load_x(t + 2, xload);  // 1x global float4 -> reg

    const unsigned char* Ab = smem + cur * 4096;
    half8 xh[2], xl[2];
#pragma unroll
    for (int m = 0; m < 2; ++m) {
      xh[m] = *(const half8*)(Ab + aOff[m]);
      xl[m] = *(const half8*)(Ab + 2048 + aOff[m]);
    }

    // hi*hi first (wh needed earliest), then xl*wh, then xh*wl (wl last ->
    // max latency cover for the lo-plane loads).
#pragma unroll
    for (int m = 0; m < 2; ++m)
#pragma unroll
      for (int n = 0; n < 4; ++n)
        acc[m][n] = __builtin_amdgcn_mfma_f32_16x16x32_f16(xh[m], wh[n], acc[m][n], 0, 0, 0);
#pragma unroll
    for (int m = 0; m < 2; ++m)
#pragma unroll
      for (int n = 0; n < 4; ++n)
        accc[m][n] = __builtin_amdgcn_mfma_f32_16x16x32_f16(xl[m], wh[n], accc[m][n], 0, 0, 0);
#pragma unroll
    for (int m = 0; m < 2; ++m)
#pragma unroll
      for (int n = 0; n < 4; ++n)
        accc[m][n] = __builtin_amdgcn_mfma_f32_16x16x32_f16(xh[m], wl[n], accc[m][n], 0, 0, 0);

    if (t + 1 < KSTEPS) {
      write_x(nxt, xcons);  // ds_write A(t+1); waits xcons's load (old)
      asm volatile("s_waitcnt lgkmcnt(0)" ::: "memory");
      __builtin_amdgcn_s_barrier();
    }
  };

  // prologue: A(0) written, X(1) in flight
  float4 xqA, xqB;
  load_x(0, xqA);
  write_x(0, xqA);
  load_x(1, xqB);
  __syncthreads();

#pragma clang loop unroll(disable)
  for (int t = 0; t < KSTEPS; t += 2) {
    body(t, xqA, xqB);      // consumes X(t+1)=xqB, loads X(t+2)->xqA
    body(t + 1, xqB, xqA);  // consumes X(t+2)=xqA, loads X(t+3)->xqB
  }
  __syncthreads();

  // ---- epilogue: sigmoid -> LDS scores [32][260] f32 (padded)
  float* sc = (float*)smem;
#pragma unroll
  for (int m = 0; m < 2; ++m)
#pragma unroll
    for (int n = 0; n < 4; ++n)
#pragma unroll
      for (int r = 0; r < 4; ++r) {
        int row = m * 16 + lg * 4 + r;
        int col = wid * 64 + n * 16 + lr;
        float v = (acc[m][n][r] + accc[m][n][r]) * DESCALE;
        sc[row * 260 + col] = 1.0f / (1.0f + expf(-v));
      }
  __syncthreads();

  // ---- fused top-8: exact lax.top_k semantics via packed (key, 255-idx) u64
  const float bb0 = bias[lane];
  const float bb1 = bias[lane + 64];
  const float bb2 = bias[lane + 128];
  const float bb3 = bias[lane + 192];
  const size_t TOT = (size_t)M_TOK * TOPK;

  for (int i = 0; i < 8; ++i) {
    int row = wid * 8 + i;
    float s0 = sc[row * 260 + lane];
    float s1 = sc[row * 260 + lane + 64];
    float s2 = sc[row * 260 + lane + 128];
    float s3 = sc[row * 260 + lane + 192];
    unsigned long long c0 = pack_ci(s0 + bb0, lane);
    unsigned long long c1 = pack_ci(s1 + bb1, lane + 64);
    unsigned long long c2 = pack_ci(s2 + bb2, lane + 128);
    unsigned long long c3 = pack_ci(s3 + bb3, lane + 192);
    float ssum = 0.f, my_s = 0.f;
    int my_idx = 0;
#pragma unroll
    for (int p = 0; p < TOPK; ++p) {
      unsigned long long b01 = c0 > c1 ? c0 : c1;
      unsigned long long b23 = c2 > c3 ? c2 : c3;
      unsigned long long best = b01 > b23 ? b01 : b23;
#pragma unroll
      for (int off = 1; off < 64; off <<= 1) {
        unsigned long long o = shflx64(best, off);
        if (o > best) best = o;
      }
      int idxw = 255 - (int)(best & 0xffull);
      int lw = idxw & 63;
      int jw = idxw >> 6;  // wave-uniform
      float sel = jw == 0 ? s0 : jw == 1 ? s1 : jw == 2 ? s2 : s3;
      float sw = __shfl(sel, lw);
      ssum += sw;
      if (lane == p) { my_idx = idxw; my_s = sw; }
      if (lane == lw) {
        if (jw == 0) c0 = 0ull;
        else if (jw == 1) c1 = 0ull;
        else if (jw == 2) c2 = 0ull;
        else c3 = 0ull;
      }
    }
    if (lane < TOPK) {
      size_t rg = (size_t)(m0 + row);
      out[rg * TOPK + lane] = (float)my_idx;                          // indices
      out[TOT + rg * TOPK + lane] = my_s * (2.5f / (ssum + 1e-20f));  // weights
    }
  }
}

extern "C" void kernel_launch(void* const* d_in, const int* in_sizes, int n_in,
                              void* d_out, int out_size, void* d_ws, size_t ws_size,
                              hipStream_t stream) {
  const float* X = (const float*)d_in[0];
  const float* W = (const float*)d_in[1];
  const float* bias = (const float*)d_in[2];
  float* out = (float*)d_out;

  const size_t wneed = (size_t)KSTEPS * WTILE;  // 7.34 MB
  if (d_ws != nullptr && ws_size >= wneed) {
    prep_w_kernel<<<KSTEPS, 256, 0, stream>>>(W, (unsigned char*)d_ws);
    gate_kernel<true><<<M_TOK / BM, 256, 0, stream>>>(
        X, W, (const unsigned char*)d_ws, bias, out);
  } else {
    gate_kernel<false><<<M_TOK / BM, 256, 0, stream>>>(X, W, nullptr, bias, out);
  }
}

// Round 9
// 260.041 us; speedup vs baseline: 2.7062x; 2.7062x over previous
//
#include <hip/hip_runtime.h>
#include <hip/hip_bf16.h>
#include <math.h>

#define M_TOK 16384
#define N_EXP 256
#define K_DIM 7168
#define BM 64
#define BK 32
#define KSTEPS (K_DIM / BK)  /* 224 */
#define KH (KSTEPS / 2)      /* 112 steps per K-half */
#define WTILE 32768          /* bytes per k-step W image: 16KB hi + 16KB lo (fp16) */
#define IMG_BYTES ((size_t)KSTEPS * WTILE)        /* 7.34 MB */
#define P_ELEMS ((size_t)M_TOK * N_EXP)           /* partial plane elems */
#define TOPK 8
#define SX 4096.0f           /* x prescale (exact pow2) */
#define SW 16384.0f          /* w prescale (exact pow2) */
#define DESCALE 1.4901161193847656e-08f /* 2^-26 = 1/(SX*SW) */

typedef __attribute__((ext_vector_type(8))) _Float16 half8;
typedef __attribute__((ext_vector_type(4))) _Float16 half4;
typedef __attribute__((ext_vector_type(4))) float f32x4;

// 2-way fp16 split of prescaled fp32: v = h + l + r, |r| <= 2^-24 |v|.
__device__ __forceinline__ void cvt8_2(const float* v, half8& h, half8& l) {
#pragma unroll
  for (int i = 0; i < 8; ++i) {
    _Float16 a = (_Float16)v[i];
    float r = v[i] - (float)a;
    h[i] = a;
    l[i] = (_Float16)r;
  }
}
__device__ __forceinline__ void cvt4_2(const float* v, half4& h, half4& l) {
#pragma unroll
  for (int i = 0; i < 4; ++i) {
    _Float16 a = (_Float16)v[i];
    float r = v[i] - (float)a;
    h[i] = a;
    l[i] = (_Float16)r;
  }
}

// monotone fp32 -> u32 key (no NaN inputs), pack with inverted index for
// lax.top_k tie-break (descending value, lowest index first on exact ties)
__device__ __forceinline__ unsigned long long pack_ci(float key, int idx) {
  unsigned int u = __builtin_bit_cast(unsigned int, key);
  u = (u & 0x80000000u) ? ~u : (u | 0x80000000u);
  return ((unsigned long long)u << 32) | (unsigned)(255 - idx);
}
__device__ __forceinline__ unsigned long long shflx64(unsigned long long v, int off) {
  int lo = __shfl_xor((int)(unsigned)(v & 0xffffffffull), off);
  int hi = __shfl_xor((int)(unsigned)(v >> 32), off);
  return ((unsigned long long)(unsigned)hi << 32) | (unsigned)lo;
}

// gate_weight fp32 [256][7168] -> per-kstep swizzled fp16 images in ws.
// Image t (32KB): hi plane [256 rows][64B] at +0, lo plane at +16384.
// byte col of 16B granule kc: (kc*16) ^ ((e&6)<<3) -- matches frag reads.
__global__ void prep_w_kernel(const float* __restrict__ W, unsigned char* __restrict__ ws) {
  int t = blockIdx.x;    // kstep
  int e = threadIdx.x;   // expert row
  const float* src = W + (size_t)e * K_DIM + t * BK;
  unsigned char* dst = ws + (size_t)t * WTILE;
#pragma unroll
  for (int kc = 0; kc < 4; ++kc) {
    float v[8];
    float4 a = ((const float4*)src)[kc * 2];
    float4 b = ((const float4*)src)[kc * 2 + 1];
    v[0] = a.x * SW; v[1] = a.y * SW; v[2] = a.z * SW; v[3] = a.w * SW;
    v[4] = b.x * SW; v[5] = b.y * SW; v[6] = b.z * SW; v[7] = b.w * SW;
    half8 h, l;
    cvt8_2(v, h, l);
    int col = (kc * 16) ^ ((e & 6) << 3);
    *(half8*)(dst + e * 64 + col) = h;
    *(half8*)(dst + 16384 + e * 64 + col) = l;
  }
}

// ---------------------------------------------------------------------------
// K-split GEMM: grid 512 = 256 M-tiles x 2 K-halves. Block g:
//   khalf = (g>>2)&1, mtile = ((g>>3)<<2)|(g&3)
// -> on round-robin XCD dispatch (xcd = g%8), XCDs 0-3 see only khalf 0 and
//    XCDs 4-7 only khalf 1: each XCD L2 holds one 3.67MB half-image (fits 4MiB).
// Writes raw fp32 partial logits (prescaled) to part[khalf][row][expert].
// ---------------------------------------------------------------------------
__global__ __launch_bounds__(512, 4) void gate_split_kernel(
    const float* __restrict__ X,
    const unsigned char* __restrict__ ws,
    float* __restrict__ part) {
  // LDS 80KB: A bufs [2][8KB] at 0 (hi 4KB, lo 4KB); W bufs [2][32KB] at
  // 16384 (hi 16KB, lo 16KB). 2 blocks/CU (2 x 81920 = 163840 = full pool).
  __shared__ unsigned char smem[81920] __attribute__((aligned(16)));

  const int g = blockIdx.x;
  const int khalf = (g >> 2) & 1;
  const int mtile = ((g >> 3) << 2) | (g & 3);
  const int m0 = mtile * BM;

  const int tid = threadIdx.x;
  const int lane = tid & 63;
  const int wid = tid >> 6;   // 0..7
  const int wm = wid >> 2;    // 0..1  (M group: rows wm*32..+32)
  const int wn = wid & 3;     // 0..3  (N group: experts wn*64..+64)
  const int lr = lane & 15;
  const int lg = lane >> 4;

  const unsigned char* img0 = ws + (size_t)khalf * KH * WTILE;

  // Frag byte offsets: lane reads row base+lr, 16B k-chunk lg, XOR-swizzled.
  int aOff[2], bOff[4];
#pragma unroll
  for (int m = 0; m < 2; ++m) {
    int r = wm * 32 + m * 16 + lr;
    aOff[m] = r * 64 + ((lg * 16) ^ ((r & 6) << 3));
  }
#pragma unroll
  for (int n = 0; n < 4; ++n) {
    int e = wn * 64 + n * 16 + lr;
    bOff[n] = e * 64 + ((lg * 16) ^ ((e & 6) << 3));
  }

  // X staging: 512 threads cover 64 rows x 8 chunks of 4 floats
  const int xr = tid >> 3;
  const int xkc = tid & 7;
  const float* xsrc = X + (size_t)(m0 + xr) * K_DIM + (size_t)khalf * KH * BK + xkc * 4;
  const int xcol = (xkc * 8) ^ ((xr & 6) << 3);

  auto load_x = [&](int t, f32x4& dst) {
    dst = __builtin_nontemporal_load((const f32x4*)(xsrc + (size_t)t * BK));
  };
  auto write_x = [&](int b, const f32x4& xv) {
    float v[4] = {xv[0] * SX, xv[1] * SX, xv[2] * SX, xv[3] * SX};
    half4 h, l;
    cvt4_2(v, h, l);
    unsigned char* Ab = smem + b * 8192;
    *(half4*)(Ab + xr * 64 + xcol) = h;
    *(half4*)(Ab + 4096 + xr * 64 + xcol) = l;
  };
  auto stage_w = [&](int t, int b) {
    unsigned char* Bb = smem + 16384 + b * 32768;
    const unsigned char* src = img0 + (size_t)t * WTILE;
#pragma unroll
    for (int i = 0; i < 4; ++i) {
      int off = i * 8192 + tid * 16;
      __builtin_amdgcn_global_load_lds(
          (const __attribute__((address_space(1))) void*)(src + off),
          (__attribute__((address_space(3))) void*)(Bb + off), 16, 0, 0);
    }
  };

  f32x4 acc[2][4];   // xh*wh (main term)
  f32x4 accc[2][4];  // correction terms xh*wl + xl*wh (<= 2^-12 of main)
#pragma unroll
  for (int m = 0; m < 2; ++m)
#pragma unroll
    for (int n = 0; n < 4; ++n) {
      acc[m][n] = (f32x4){0.f, 0.f, 0.f, 0.f};
      accc[m][n] = (f32x4){0.f, 0.f, 0.f, 0.f};
    }

  // One pipeline stage. Consumes xcons (=X(t+1)), loads X(t+2) into xload.
  // Counted vmcnt(1): drain my 4 W-staging loads pre-barrier; X(t+2) stays
  // in flight across the barrier.
  auto body = [&](int t, f32x4& xload, const f32x4& xcons) {
    const int cur = t & 1, nxt = cur ^ 1;
    if (t + 1 < KH) stage_w(t + 1, nxt);   // 4x global_load_lds (16B)
    if (t + 2 < KH) load_x(t + 2, xload);  // 1x global f32x4 -> reg (NT)

    const unsigned char* Ab = smem + cur * 8192;
    const unsigned char* Bb = smem + 16384 + cur * 32768;
    half8 xh[2], xl[2], wh[4], wl[4];
#pragma unroll
    for (int m = 0; m < 2; ++m) {
      xh[m] = *(const half8*)(Ab + aOff[m]);
      xl[m] = *(const half8*)(Ab + 4096 + aOff[m]);
    }
#pragma unroll
    for (int n = 0; n < 4; ++n) {
      wh[n] = *(const half8*)(Bb + bOff[n]);
      wl[n] = *(const half8*)(Bb + 16384 + bOff[n]);
    }
#pragma unroll
    for (int m = 0; m < 2; ++m)
#pragma unroll
      for (int n = 0; n < 4; ++n) {
        acc[m][n] = __builtin_amdgcn_mfma_f32_16x16x32_f16(xh[m], wh[n], acc[m][n], 0, 0, 0);
        f32x4 c = accc[m][n];
        c = __builtin_amdgcn_mfma_f32_16x16x32_f16(xh[m], wl[n], c, 0, 0, 0);
        c = __builtin_amdgcn_mfma_f32_16x16x32_f16(xl[m], wh[n], c, 0, 0, 0);
        accc[m][n] = c;
      }

    if (t + 1 < KH) {
      write_x(nxt, xcons);  // compiler emits counted vmcnt for xcons's load
      if (t + 2 < KH) {
        asm volatile("s_waitcnt vmcnt(1)" ::: "memory");
      } else {
        asm volatile("s_waitcnt vmcnt(0)" ::: "memory");
      }
      asm volatile("s_waitcnt lgkmcnt(0)" ::: "memory");
      __builtin_amdgcn_s_barrier();
    }
  };

  // prologue: W(0) staged+drained, A(0) written, X(1) in flight
  f32x4 xqA, xqB;
  stage_w(0, 0);
  load_x(0, xqA);
  write_x(0, xqA);   // auto-wait drains W(0) too (issued before X(0))
  load_x(1, xqB);    // issued after write_x's wait -> stays in flight
  __syncthreads();

#pragma clang loop unroll(disable)
  for (int t = 0; t < KH; t += 2) {
    body(t, xqA, xqB);      // consumes X(t+1)=xqB, loads X(t+2)->xqA
    body(t + 1, xqB, xqA);  // consumes X(t+2)=xqA, loads X(t+3)->xqB
  }

  // ---- epilogue: raw prescaled partial logits -> part[khalf] (NT stores;
  // 4B lanes land as full 64B segments: 16 consecutive cols per (m,n,r))
  float* dst = part + (size_t)khalf * P_ELEMS;
#pragma unroll
  for (int m = 0; m < 2; ++m)
#pragma unroll
    for (int n = 0; n < 4; ++n)
#pragma unroll
      for (int r = 0; r < 4; ++r) {
        int row = wm * 32 + m * 16 + lg * 4 + r;
        int col = wn * 64 + n * 16 + lr;
        __builtin_nontemporal_store(acc[m][n][r] + accc[m][n][r],
                                    &dst[(size_t)(m0 + row) * N_EXP + col]);
      }
}

// ---------------------------------------------------------------------------
// Reducer: add the two K-half partials, descale, sigmoid, fused top-8.
// Grid 512 x 256 threads; block handles 32 rows.
// ---------------------------------------------------------------------------
__global__ __launch_bounds__(256) void reduce_topk_kernel(
    const float* __restrict__ part,
    const float* __restrict__ bias,
    float* __restrict__ out) {
  __shared__ float sc[32 * 260];

  const int tid = threadIdx.x;
  const int lane = tid & 63;
  const int wid = tid >> 6;  // 0..3
  const int r0 = blockIdx.x * 32;

  const float* p0 = part;
  const float* p1 = part + P_ELEMS;

  // load+add+sigmoid: thread covers row tid>>3, cols (tid&7)*32..+32
  {
    int row = tid >> 3, seg = tid & 7;
    size_t base = (size_t)(r0 + row) * N_EXP + seg * 32;
#pragma unroll
    for (int j = 0; j < 8; ++j) {
      f32x4 a = __builtin_nontemporal_load((const f32x4*)(p0 + base + j * 4));
      f32x4 b = __builtin_nontemporal_load((const f32x4*)(p1 + base + j * 4));
#pragma unroll
      for (int e = 0; e < 4; ++e) {
        float v = (a[e] + b[e]) * DESCALE;
        sc[row * 260 + seg * 32 + j * 4 + e] = 1.0f / (1.0f + expf(-v));
      }
    }
  }
  __syncthreads();

  // fused top-8: exact lax.top_k semantics via packed (key, 255-idx) u64
  const float bb0 = bias[lane];
  const float bb1 = bias[lane + 64];
  const float bb2 = bias[lane + 128];
  const float bb3 = bias[lane + 192];
  const size_t TOT = (size_t)M_TOK * TOPK;

  for (int i = 0; i < 8; ++i) {
    int row = wid * 8 + i;
    float s0 = sc[row * 260 + lane];
    float s1 = sc[row * 260 + lane + 64];
    float s2 = sc[row * 260 + lane + 128];
    float s3 = sc[row * 260 + lane + 192];
    unsigned long long c0 = pack_ci(s0 + bb0, lane);
    unsigned long long c1 = pack_ci(s1 + bb1, lane + 64);
    unsigned long long c2 = pack_ci(s2 + bb2, lane + 128);
    unsigned long long c3 = pack_ci(s3 + bb3, lane + 192);
    float ssum = 0.f, my_s = 0.f;
    int my_idx = 0;
#pragma unroll
    for (int p = 0; p < TOPK; ++p) {
      unsigned long long b01 = c0 > c1 ? c0 : c1;
      unsigned long long b23 = c2 > c3 ? c2 : c3;
      unsigned long long best = b01 > b23 ? b01 : b23;
#pragma unroll
      for (int off = 1; off < 64; off <<= 1) {
        unsigned long long o = shflx64(best, off);
        if (o > best) best = o;
      }
      int idxw = 255 - (int)(best & 0xffull);
      int lw = idxw & 63;
      int jw = idxw >> 6;  // wave-uniform
      float sel = jw == 0 ? s0 : jw == 1 ? s1 : jw == 2 ? s2 : s3;
      float sw = __shfl(sel, lw);
      ssum += sw;
      if (lane == p) { my_idx = idxw; my_s = sw; }
      if (lane == lw) {
        if (jw == 0) c0 = 0ull;
        else if (jw == 1) c1 = 0ull;
        else if (jw == 2) c2 = 0ull;
        else c3 = 0ull;
      }
    }
    if (lane < TOPK) {
      size_t rg = (size_t)(r0 + row);
      out[rg * TOPK + lane] = (float)my_idx;                          // indices
      out[TOT + rg * TOPK + lane] = my_s * (2.5f / (ssum + 1e-20f));  // weights
    }
  }
}

// ---------------------------------------------------------------------------
// Fallback (ws too small): round-6-style monolithic kernel, W from Wg with
// on-the-fly split. Grid 256 x 512 threads.
// ---------------------------------------------------------------------------
__global__ __launch_bounds__(512, 2) void gate_mono_kernel(
    const float* __restrict__ X,
    const float* __restrict__ Wg,
    const float* __restrict__ bias,
    float* __restrict__ out) {
  __shared__ unsigned char smem[81920] __attribute__((aligned(16)));

  const int tid = threadIdx.x;
  const int lane = tid & 63;
  const int wid = tid >> 6;
  const int wm = wid >> 2;
  const int wn = wid & 3;
  const int lr = lane & 15;
  const int lg = lane >> 4;
  const int m0 = blockIdx.x * BM;

  int aOff[2], bOff[4];
#pragma unroll
  for (int m = 0; m < 2; ++m) {
    int r = wm * 32 + m * 16 + lr;
    aOff[m] = r * 64 + ((lg * 16) ^ ((r & 6) << 3));
  }
#pragma unroll
  for (int n = 0; n < 4; ++n) {
    int e = wn * 64 + n * 16 + lr;
    bOff[n] = e * 64 + ((lg * 16) ^ ((e & 6) << 3));
  }

  const int xr = tid >> 3;
  const int xkc = tid & 7;
  const float* xsrc = X + (size_t)(m0 + xr) * K_DIM + xkc * 4;
  const int xcol = (xkc * 8) ^ ((xr & 6) << 3);

  auto load_x = [&](int t, f32x4& dst) {
    dst = *(const f32x4*)(xsrc + (size_t)t * BK);
  };
  auto write_x = [&](int b, const f32x4& xv) {
    float v[4] = {xv[0] * SX, xv[1] * SX, xv[2] * SX, xv[3] * SX};
    half4 h, l;
    cvt4_2(v, h, l);
    unsigned char* Ab = smem + b * 8192;
    *(half4*)(Ab + xr * 64 + xcol) = h;
    *(half4*)(Ab + 4096 + xr * 64 + xcol) = l;
  };
  auto stage_w = [&](int t, int b) {
    unsigned char* Bb = smem + 16384 + b * 32768;
    int row = tid >> 1;
    int g0 = (tid & 1) * 2;
    const float* src = Wg + (size_t)row * K_DIM + (size_t)t * BK + g0 * 8;
#pragma unroll
    for (int g = 0; g < 2; ++g) {
      float v[8];
      float4 a = ((const float4*)src)[g * 2];
      float4 bq = ((const float4*)src)[g * 2 + 1];
      v[0] = a.x * SW; v[1] = a.y * SW; v[2] = a.z * SW; v[3] = a.w * SW;
      v[4] = bq.x * SW; v[5] = bq.y * SW; v[6] = bq.z * SW; v[7] = bq.w * SW;
      half8 h, l;
      cvt8_2(v, h, l);
      int col = ((g0 + g) * 16) ^ ((row & 6) << 3);
      *(half8*)(Bb + row * 64 + col) = h;
      *(half8*)(Bb + 16384 + row * 64 + col) = l;
    }
  };

  f32x4 acc[2][4], accc[2][4];
#pragma unroll
  for (int m = 0; m < 2; ++m)
#pragma unroll
    for (int n = 0; n < 4; ++n) {
      acc[m][n] = (f32x4){0.f, 0.f, 0.f, 0.f};
      accc[m][n] = (f32x4){0.f, 0.f, 0.f, 0.f};
    }

  f32x4 xqA, xqB;
  stage_w(0, 0);
  load_x(0, xqA);
  write_x(0, xqA);
  load_x(1, xqB);
  __syncthreads();

#pragma clang loop unroll(disable)
  for (int t = 0; t < KSTEPS; ++t) {
    const int cur = t & 1, nxt = cur ^ 1;
    f32x4& xload = (t & 1) ? xqB : xqA;
    const f32x4& xcons = (t & 1) ? xqA : xqB;
    if (t + 1 < KSTEPS) stage_w(t + 1, nxt);
    if (t + 2 < KSTEPS) load_x(t + 2, xload);

    const unsigned char* Ab = smem + cur * 8192;
    const unsigned char* Bb = smem + 16384 + cur * 32768;
    half8 xh[2], xl[2], wh[4], wl[4];
#pragma unroll
    for (int m = 0; m < 2; ++m) {
      xh[m] = *(const half8*)(Ab + aOff[m]);
      xl[m] = *(const half8*)(Ab + 2048 * 2 + aOff[m]);
    }
#pragma unroll
    for (int n = 0; n < 4; ++n) {
      wh[n] = *(const half8*)(Bb + bOff[n]);
      wl[n] = *(const half8*)(Bb + 16384 + bOff[n]);
    }
#pragma unroll
    for (int m = 0; m < 2; ++m)
#pragma unroll
      for (int n = 0; n < 4; ++n) {
        acc[m][n] = __builtin_amdgcn_mfma_f32_16x16x32_f16(xh[m], wh[n], acc[m][n], 0, 0, 0);
        f32x4 c = accc[m][n];
        c = __builtin_amdgcn_mfma_f32_16x16x32_f16(xh[m], wl[n], c, 0, 0, 0);
        c = __builtin_amdgcn_mfma_f32_16x16x32_f16(xl[m], wh[n], c, 0, 0, 0);
        accc[m][n] = c;
      }
    if (t + 1 < KSTEPS) {
      write_x(nxt, xcons);
      __syncthreads();
    }
  }
  __syncthreads();

  float* sc = (float*)smem;
#pragma unroll
  for (int m = 0; m < 2; ++m)
#pragma unroll
    for (int n = 0; n < 4; ++n)
#pragma unroll
      for (int r = 0; r < 4; ++r) {
        int row = wm * 32 + m * 16 + lg * 4 + r;
        int col = wn * 64 + n * 16 + lr;
        float v = (acc[m][n][r] + accc[m][n][r]) * DESCALE;
        sc[row * 260 + col] = 1.0f / (1.0f + expf(-v));
      }
  __syncthreads();

  const float bb0 = bias[lane];
  const float bb1 = bias[lane + 64];
  const float bb2 = bias[lane + 128];
  const float bb3 = bias[lane + 192];
  const size_t TOT = (size_t)M_TOK * TOPK;

  for (int i = 0; i < 8; ++i) {
    int row = wid * 8 + i;
    float s0 = sc[row * 260 + lane];
    float s1 = sc[row * 260 + lane + 64];
    float s2 = sc[row * 260 + lane + 128];
    float s3 = sc[row * 260 + lane + 192];
    unsigned long long c0 = pack_ci(s0 + bb0, lane);
    unsigned long long c1 = pack_ci(s1 + bb1, lane + 64);
    unsigned long long c2 = pack_ci(s2 + bb2, lane + 128);
    unsigned long long c3 = pack_ci(s3 + bb3, lane + 192);
    float ssum = 0.f, my_s = 0.f;
    int my_idx = 0;
#pragma unroll
    for (int p = 0; p < TOPK; ++p) {
      unsigned long long b01 = c0 > c1 ? c0 : c1;
      unsigned long long b23 = c2 > c3 ? c2 : c3;
      unsigned long long best = b01 > b23 ? b01 : b23;
#pragma unroll
      for (int off = 1; off < 64; off <<= 1) {
        unsigned long long o = shflx64(best, off);
        if (o > best) best = o;
      }
      int idxw = 255 - (int)(best & 0xffull);
      int lw = idxw & 63;
      int jw = idxw >> 6;
      float sel = jw == 0 ? s0 : jw == 1 ? s1 : jw == 2 ? s2 : s3;
      float sw = __shfl(sel, lw);
      ssum += sw;
      if (lane == p) { my_idx = idxw; my_s = sw; }
      if (lane == lw) {
        if (jw == 0) c0 = 0ull;
        else if (jw == 1) c1 = 0ull;
        else if (jw == 2) c2 = 0ull;
        else c3 = 0ull;
      }
    }
    if (lane < TOPK) {
      size_t rg = (size_t)(m0 + row);
      out[rg * TOPK + lane] = (float)my_idx;
      out[TOT + rg * TOPK + lane] = my_s * (2.5f / (ssum + 1e-20f));
    }
  }
}

extern "C" void kernel_launch(void* const* d_in, const int* in_sizes, int n_in,
                              void* d_out, int out_size, void* d_ws, size_t ws_size,
                              hipStream_t stream) {
  const float* X = (const float*)d_in[0];
  const float* W = (const float*)d_in[1];
  const float* bias = (const float*)d_in[2];
  float* out = (float*)d_out;

  const size_t need = IMG_BYTES + 2 * P_ELEMS * sizeof(float);  // ~40.9 MB
  if (d_ws != nullptr && ws_size >= need) {
    unsigned char* ws = (unsigned char*)d_ws;
    float* part = (float*)(ws + IMG_BYTES);
    prep_w_kernel<<<KSTEPS, 256, 0, stream>>>(W, ws);
    gate_split_kernel<<<2 * (M_TOK / BM), 512, 0, stream>>>(X, ws, part);
    reduce_topk_kernel<<<M_TOK / 32, 256, 0, stream>>>(part, bias, out);
  } else {
    gate_mono_kernel<<<M_TOK / BM, 512, 0, stream>>>(X, W, bias, out);
  }
}